// Round 3
// baseline (819.280 us; speedup 1.0000x reference)
//
#include <hip/hip_runtime.h>

#define B_ 16
#define NF_ 16
#define N_ 1024
#define D_ 128
#define S_ 8
#define SCALE_ 0.08838834764831845f
#define LDX 129  // fp32 LDS row stride: 129 mod 32 == 1 -> conflict-free row & column access

// acc += dot(fp32 row of 128, fp32 x[128]); acc starts at bias
__device__ __forceinline__ float dot128f(const float* __restrict__ wrow, const float* x, float acc) {
  const float4* w = (const float4*)wrow;
#pragma unroll
  for (int i = 0; i < 32; ++i) {
    float4 v = w[i];
    const float* xx = x + i * 4;
    acc += v.x * xx[0] + v.y * xx[1] + v.z * xx[2] + v.w * xx[3];
  }
  return acc;
}

// Block-wide mean / rsqrt(var+eps) over 128 values held by threads t<128.
// ALL threads of the block must call this (contains __syncthreads).
__device__ __forceinline__ void stats128(float v, int t, float* red, float& m, float& inv, float eps) {
  __syncthreads();
  float s = (t < 128) ? v : 0.f;
  float s2 = (t < 128) ? v * v : 0.f;
#pragma unroll
  for (int off = 32; off; off >>= 1) { s += __shfl_down(s, off); s2 += __shfl_down(s2, off); }
  if (t == 0)  { red[0] = s; red[2] = s2; }
  if (t == 64) { red[1] = s; red[3] = s2; }
  __syncthreads();
  m = (red[0] + red[1]) * (1.f / 128.f);
  float var = (red[2] + red[3]) * (1.f / 128.f) - m * m;
  inv = rsqrtf(var + eps);
}

// q (in shared, fp32) -> qW[t] = sum_d q[d]*Wk[d][t] (= q@Wk), qb = q . bk
__device__ __forceinline__ void project_q(const float* q_sh, const float* __restrict__ Wk,
    const float* __restrict__ bk, float* red, int t, int bs,
    float* __restrict__ qW, float* __restrict__ qb) {
  if (t < 128) {
    float a = 0.f;
#pragma unroll 16
    for (int d = 0; d < 128; ++d) a += q_sh[d] * Wk[d * 128 + t];
    qW[bs * 128 + t] = a;
    float p = q_sh[t] * bk[t];
#pragma unroll
    for (int off = 32; off; off >>= 1) p += __shfl_down(p, off);
    if (t == 0)  red[0] = p;
    if (t == 64) red[1] = p;
  }
  __syncthreads();
  if (t == 0) qb[bs] = red[0] + red[1];
}

// ---------------- init: slots = broadcast(slots_init); q = LN_sl(slots)@Wq^T+bq; qW,qb ----------------
__global__ __launch_bounds__(128) void init_kernel(
    const float* __restrict__ slots_init,
    const float* __restrict__ g_sl, const float* __restrict__ be_sl,
    const float* __restrict__ Wq, const float* __restrict__ bq,
    const float* __restrict__ Wk, const float* __restrict__ bk,
    float* __restrict__ slots, float* __restrict__ qW, float* __restrict__ qb) {
  int t = threadIdx.x;
  int b = blockIdx.x >> 3, s = blockIdx.x & 7;
  __shared__ float buf[128], q_sh[128];
  __shared__ float red[4];
  float v = slots_init[s * 128 + t];
  slots[(b * 8 + s) * 128 + t] = v;
  float m, inv;
  stats128(v, t, red, m, inv, 1e-5f);
  buf[t] = (v - m) * inv * g_sl[t] + be_sl[t];
  __syncthreads();
  q_sh[t] = dot128f(Wq + t * 128, buf, bq[t]);
  __syncthreads();
  project_q(q_sh, Wk, bk, red, t, b * 8 + s, qW, qb);
}

// ---------------- attn: LN(x) tile in LDS, dots via qW, softmax over S, P/S partials ----------------
// grid = 16 b * 16 jtiles (64 rows each), 256 threads.
__global__ __launch_bounds__(256) void attn_kernel(
    const float* __restrict__ x,
    const float* __restrict__ g_in, const float* __restrict__ be_in,
    const float* __restrict__ qW, const float* __restrict__ qb,
    float* __restrict__ P_part, float* __restrict__ S_part,
    float* __restrict__ out_attn, int f, int wo) {
  __shared__ float Xt[64 * LDX];
  __shared__ float qWs[8 * 128];
  __shared__ float at[8 * 64];
  __shared__ float qbs[8];
  __shared__ float rowsum[64], rowsum2[64];
  int t = threadIdx.x;
  int b = blockIdx.x >> 4, jt = blockIdx.x & 15;
  long xbase = (((long)b * NF_ + f) * N_ + jt * 64) * D_;

  // stage raw x tile (64x128 fp32) into LDS
#pragma unroll
  for (int i = 0; i < 8; ++i) {
    int chunk = t + i * 256;           // 0..2047 float4s
    int r = chunk >> 5, c = (chunk & 31) * 4;
    float4 raw = *(const float4*)(x + xbase + r * D_ + c);
    float* dst = Xt + r * LDX + c;
    dst[0] = raw.x; dst[1] = raw.y; dst[2] = raw.z; dst[3] = raw.w;
  }
#pragma unroll
  for (int i = 0; i < 4; ++i) {
    int idx = t + i * 256;
    qWs[idx] = qW[b * (S_ * D_) + idx];
  }
  if (t < 8) qbs[t] = qb[b * 8 + t];
  __syncthreads();

  // per-row LN stats: 4 threads per row, 32 elems each
  int r = t >> 2, p4 = t & 3;
  {
    const float* row = Xt + r * LDX + p4 * 32;
    float s1 = 0.f, s2 = 0.f;
#pragma unroll
    for (int i = 0; i < 32; ++i) { float v = row[i]; s1 += v; s2 += v * v; }
    s1 += __shfl_down(s1, 1); s2 += __shfl_down(s2, 1);
    s1 += __shfl_down(s1, 2); s2 += __shfl_down(s2, 2);
    if (p4 == 0) { rowsum[r] = s1; rowsum2[r] = s2; }
  }
  __syncthreads();
  {
    float m = rowsum[r] * (1.f / 128.f);
    float var = rowsum2[r] * (1.f / 128.f) - m * m;
    float inv = rsqrtf(var + 1e-5f);
    float* row = Xt + r * LDX + p4 * 32;
    const float* gg = g_in + p4 * 32;
    const float* bb = be_in + p4 * 32;
#pragma unroll
    for (int i = 0; i < 32; ++i)
      row[i] = (row[i] - m) * inv * gg[i] + bb[i];
  }
  __syncthreads();

  // dots: thread (j = t&63, sh = t>>6) computes slots 2sh, 2sh+1
  {
    int j = t & 63, sh = t >> 6;
    const float* q0 = qWs + (2 * sh) * 128;
    const float* q1 = qWs + (2 * sh + 1) * 128;
    const float* xr = Xt + j * LDX;
    float d0 = 0.f, d1 = 0.f;
#pragma unroll
    for (int k = 0; k < 128; ++k) {
      float xv = xr[k];
      d0 += xv * q0[k];
      d1 += xv * q1[k];
    }
    at[(2 * sh) * 64 + j]     = (d0 + qbs[2 * sh])     * SCALE_;
    at[(2 * sh + 1) * 64 + j] = (d1 + qbs[2 * sh + 1]) * SCALE_;
  }
  __syncthreads();

  // softmax over the 8 slots per column j, +EPS; attn_ori out; per-block S partials
  if (t < 64) {
    float vals[8];
    float mx = -1e30f;
#pragma unroll
    for (int s = 0; s < 8; ++s) { vals[s] = at[s * 64 + t]; mx = fmaxf(mx, vals[s]); }
    float sum = 0.f;
#pragma unroll
    for (int s = 0; s < 8; ++s) { vals[s] = __expf(vals[s] - mx); sum += vals[s]; }
    float rr = 1.f / sum;
#pragma unroll
    for (int s = 0; s < 8; ++s) {
      vals[s] = vals[s] * rr + 1e-8f;
      at[s * 64 + t] = vals[s];
    }
    if (wo) {
#pragma unroll
      for (int s = 0; s < 8; ++s)
        out_attn[(((long)b * NF_ + f) * S_ + s) * N_ + jt * 64 + t] = vals[s];
    }
#pragma unroll
    for (int s = 0; s < 8; ++s) {
      float v = vals[s];
#pragma unroll
      for (int off = 32; off; off >>= 1) v += __shfl_down(v, off);
      if (t == 0) S_part[(b * 16 + jt) * 8 + s] = v;
    }
  }
  __syncthreads();

  // P partials: P[s][k] = sum_j attn_ori[s][j] * xn[j][k]
  {
    int k = t & 127, h = t >> 7;  // h=0: s 0..3, h=1: s 4..7
    float u0 = 0.f, u1 = 0.f, u2 = 0.f, u3 = 0.f;
    const float* a0 = at + (h * 4 + 0) * 64;
    const float* a1 = at + (h * 4 + 1) * 64;
    const float* a2 = at + (h * 4 + 2) * 64;
    const float* a3 = at + (h * 4 + 3) * 64;
#pragma unroll 8
    for (int j = 0; j < 64; ++j) {
      float xv = Xt[j * LDX + k];
      u0 += xv * a0[j]; u1 += xv * a1[j]; u2 += xv * a2[j]; u3 += xv * a3[j];
    }
    float* pp = P_part + (long)(b * 16 + jt) * 8 * 128;
    pp[(h * 4 + 0) * 128 + k] = u0;
    pp[(h * 4 + 1) * 128 + k] = u1;
    pp[(h * 4 + 2) * 128 + k] = u2;
    pp[(h * 4 + 3) * 128 + k] = u3;
  }
}

// ---------------- update: reduce P, updates=Wv.(P/S)+bv, GRU, FF, slots out, next q/qW/qb ----------------
// grid = 128 (b,s), 384 threads.
__global__ __launch_bounds__(384) void update_kernel(
    const float* __restrict__ P_part, const float* __restrict__ S_part,
    const float* __restrict__ Wih, const float* __restrict__ Whh,
    const float* __restrict__ bih, const float* __restrict__ bhh,
    const float* __restrict__ W1, const float* __restrict__ b1,
    const float* __restrict__ W2, const float* __restrict__ b2,
    const float* __restrict__ g_ff, const float* __restrict__ be_ff,
    const float* __restrict__ g_sl, const float* __restrict__ be_sl,
    const float* __restrict__ Wq, const float* __restrict__ bq,
    const float* __restrict__ Wk, const float* __restrict__ bk,
    const float* __restrict__ Wv, const float* __restrict__ bv,
    float* __restrict__ slots, float* __restrict__ qW, float* __restrict__ qb,
    float* __restrict__ out_slots, int f, int wo) {
  int t = threadIdx.x;
  int b = blockIdx.x >> 3, s = blockIdx.x & 7;
  __shared__ float Pk[128], hprev[128], upd[128], hn[128], buf[128], hid[128], q_sh[128];
  __shared__ float giS[384], ghS[384];
  __shared__ float red[4];

  if (t < 128) {
    float pa = 0.f;
#pragma unroll
    for (int jt = 0; jt < 16; ++jt) pa += P_part[((b * 16 + jt) * 8 + s) * 128 + t];
    float ss = 0.f;
#pragma unroll
    for (int jt = 0; jt < 16; ++jt) ss += S_part[(b * 16 + jt) * 8 + s];
    Pk[t] = pa / ss;
    hprev[t] = slots[(b * 8 + s) * 128 + t];
  }
  __syncthreads();
  if (t < 128) upd[t] = dot128f(Wv + t * 128, Pk, bv[t]);
  __syncthreads();
  giS[t] = dot128f(Wih + t * 128, upd, bih[t]);
  ghS[t] = dot128f(Whh + t * 128, hprev, bhh[t]);
  __syncthreads();
  if (t < 128) {
    float r = 1.f / (1.f + expf(-(giS[t] + ghS[t])));
    float z = 1.f / (1.f + expf(-(giS[128 + t] + ghS[128 + t])));
    float n = tanhf(giS[256 + t] + r * ghS[256 + t]);
    hn[t] = (1.f - z) * n + z * hprev[t];
  }
  __syncthreads();
  // FF: LN_ff -> W1/relu -> W2, residual
  float m, inv;
  float hv = (t < 128) ? hn[t] : 0.f;
  stats128(hv, t, red, m, inv, 1e-5f);
  if (t < 128) buf[t] = (hv - m) * inv * g_ff[t] + be_ff[t];
  __syncthreads();
  if (t < 128) hid[t] = fmaxf(dot128f(W1 + t * 128, buf, b1[t]), 0.f);
  __syncthreads();
  if (t < 128) {
    float ffv = dot128f(W2 + t * 128, hid, b2[t]);
    float sn = hn[t] + ffv;
    slots[(b * 8 + s) * 128 + t] = sn;
    if (wo) out_slots[(((long)b * NF_ + f) * S_ + s) * 128 + t] = sn;
    buf[t] = sn;
  }
  __syncthreads();
  // next-frame q: LN_sl(new slots) @ Wq^T + bq, then qW = q@Wk, qb = q.bk
  float sv = (t < 128) ? buf[t] : 0.f;
  stats128(sv, t, red, m, inv, 1e-5f);
  if (t < 128) hid[t] = (sv - m) * inv * g_sl[t] + be_sl[t];
  __syncthreads();
  if (t < 128) q_sh[t] = dot128f(Wq + t * 128, hid, bq[t]);
  __syncthreads();
  project_q(q_sh, Wk, bk, red, t, b * 8 + s, qW, qb);
}

extern "C" void kernel_launch(void* const* d_in, const int* in_sizes, int n_in,
                              void* d_out, int out_size, void* d_ws, size_t ws_size,
                              hipStream_t stream) {
  const float* inputs     = (const float*)d_in[0];
  const float* slots_init = (const float*)d_in[1];
  const float* Wq  = (const float*)d_in[2];
  const float* bq  = (const float*)d_in[3];
  const float* Wk  = (const float*)d_in[4];
  const float* bk  = (const float*)d_in[5];
  const float* Wv  = (const float*)d_in[6];
  const float* bv  = (const float*)d_in[7];
  const float* W1  = (const float*)d_in[8];
  const float* b1  = (const float*)d_in[9];
  const float* W2  = (const float*)d_in[10];
  const float* b2  = (const float*)d_in[11];
  const float* Wih = (const float*)d_in[12];
  const float* Whh = (const float*)d_in[13];
  const float* bih = (const float*)d_in[14];
  const float* bhh = (const float*)d_in[15];
  const float* g_in  = (const float*)d_in[16];
  const float* be_in = (const float*)d_in[17];
  const float* g_sl  = (const float*)d_in[18];
  const float* be_sl = (const float*)d_in[19];
  const float* g_ff  = (const float*)d_in[20];
  const float* be_ff = (const float*)d_in[21];

  float* out_slots = (float*)d_out;
  float* out_attn  = out_slots + (size_t)B_ * NF_ * S_ * D_;

  // workspace layout (total ~1.2 MB)
  char* ws = (char*)d_ws;
  float* slots  = (float*)(ws);                     //  64 KB (16*8*128 f32)
  float* qW     = (float*)(ws + 65536);             //  64 KB
  float* qb     = (float*)(ws + 131072);            //  512 B
  float* P_part = (float*)(ws + 131584);            //   1 MB (256*8*128 f32)
  float* S_part = (float*)(ws + 131584 + 1048576);  //   8 KB

  init_kernel<<<128, 128, 0, stream>>>(slots_init, g_sl, be_sl, Wq, bq, Wk, bk,
                                       slots, qW, qb);

  for (int it = 0; it < 17; ++it) {
    int f = (it == 0) ? 0 : it - 1;
    int wo = (it > 0) ? 1 : 0;
    attn_kernel<<<256, 256, 0, stream>>>(inputs, g_in, be_in, qW, qb,
                                         P_part, S_part, out_attn, f, wo);
    update_kernel<<<128, 384, 0, stream>>>(P_part, S_part, Wih, Whh, bih, bhh,
        W1, b1, W2, b2, g_ff, be_ff, g_sl, be_sl, Wq, bq, Wk, bk, Wv, bv,
        slots, qW, qb, out_slots, f, wo);
  }
}